// Round 6
// baseline (626.939 us; speedup 1.0000x reference)
//
#include <hip/hip_runtime.h>

typedef short short8 __attribute__((ext_vector_type(8)));
typedef float f32x4 __attribute__((ext_vector_type(4)));
typedef float f32x16 __attribute__((ext_vector_type(16)));
typedef unsigned short ushort_t;
typedef unsigned int uint_t;

#define HD __device__ __forceinline__

HD ushort_t f2bf(float f) {  // round-to-nearest-even f32 -> bf16 bits
    uint_t u = __float_as_uint(f);
    uint_t r = (u + 0x7fffu + ((u >> 16) & 1u)) >> 16;
    return (ushort_t)r;
}
HD float bf2f(ushort_t h) { return __uint_as_float(((uint_t)h) << 16); }
HD float readlane_f(float v, int l) {
    return __int_as_float(__builtin_amdgcn_readlane(__float_as_int(v), l));
}

HD void pack_hilo(const float* v8, short8& h, short8& l) {
#pragma unroll
    for (int e = 0; e < 8; ++e) {
        ushort_t hh = f2bf(v8[e]);
        h[e] = (short)hh;
        l[e] = (short)f2bf(v8[e] - bf2f(hh));
    }
}

// ---------------- MFMA hi/lo split GEMM: C[M,Ntot] = A[M,K] @ B ----------------
__global__ __launch_bounds__(256) void gemm_mfma_hilo(
    const float* __restrict__ A, const ushort_t* __restrict__ Bth,
    const ushort_t* __restrict__ Btl, float* __restrict__ C,
    int M, int K, int Ntot) {
    __shared__ ushort_t Ah[128][72], Al[128][72], Bh[128][72], Bl[128][72];
    int tid = threadIdx.x;
    int lane = tid & 63, w = tid >> 6;
    int row0 = blockIdx.x * 128;
    int col0 = blockIdx.y * 128;
    int cl = lane & 31, hi = lane >> 5;
    f32x16 acc[4] = {};
    for (int k0 = 0; k0 < K; k0 += 64) {
        for (int e = tid; e < 4096; e += 256) {
            int r = e >> 5, k2 = e & 31;
            int gr = row0 + r;
            float2 v = {0.f, 0.f};
            if (gr < M) v = *(const float2*)&A[(long)gr * K + k0 + k2 * 2];
            ushort_t h0 = f2bf(v.x); ushort_t l0 = f2bf(v.x - bf2f(h0));
            ushort_t h1 = f2bf(v.y); ushort_t l1 = f2bf(v.y - bf2f(h1));
            *(uint_t*)&Ah[r][k2 * 2] = (uint_t)h0 | ((uint_t)h1 << 16);
            *(uint_t*)&Al[r][k2 * 2] = (uint_t)l0 | ((uint_t)l1 << 16);
        }
        for (int e = tid; e < 4096; e += 256) {
            int n = e >> 5, k2 = e & 31;
            const uint_t* ph = (const uint_t*)&Bth[(long)(col0 + n) * K + k0];
            const uint_t* pl = (const uint_t*)&Btl[(long)(col0 + n) * K + k0];
            *(uint_t*)&Bh[n][k2 * 2] = ph[k2];
            *(uint_t*)&Bl[n][k2 * 2] = pl[k2];
        }
        __syncthreads();
        int arow = w * 32 + cl;
#pragma unroll
        for (int kk = 0; kk < 4; ++kk) {
            int koff = kk * 16 + hi * 8;
            short8 a_h = *(const short8*)&Ah[arow][koff];
            short8 a_l = *(const short8*)&Al[arow][koff];
#pragma unroll
            for (int nf = 0; nf < 4; ++nf) {
                int bcol = nf * 32 + cl;
                short8 b_h = *(const short8*)&Bh[bcol][koff];
                short8 b_l = *(const short8*)&Bl[bcol][koff];
                acc[nf] = __builtin_amdgcn_mfma_f32_32x32x16_bf16(a_h, b_h, acc[nf], 0, 0, 0);
                acc[nf] = __builtin_amdgcn_mfma_f32_32x32x16_bf16(a_l, b_h, acc[nf], 0, 0, 0);
                acc[nf] = __builtin_amdgcn_mfma_f32_32x32x16_bf16(a_h, b_l, acc[nf], 0, 0, 0);
            }
        }
        __syncthreads();
    }
#pragma unroll
    for (int nf = 0; nf < 4; ++nf) {
#pragma unroll
        for (int reg = 0; reg < 16; ++reg) {
            int crow = (reg & 3) + 8 * (reg >> 2) + 4 * hi + w * 32;
            int gr = row0 + crow;
            if (gr < M) C[(long)gr * Ntot + col0 + nf * 32 + cl] = acc[nf][reg];
        }
    }
}

// ---------------- weight prep ----------------
__global__ void prep_bt_conv(const float* __restrict__ Wc, ushort_t* bh, ushort_t* bl) {
    int idx = blockIdx.x * 256 + threadIdx.x;
    if (idx >= 128 * 256) return;
    int n = idx >> 8, k = idx & 255;
    float v = Wc[k * 128 + n];
    ushort_t h = f2bf(v);
    bh[idx] = h;
    bl[idx] = f2bf(v - bf2f(h));
}

// w1t[m][n][k] = hi/lo bf16 of W1[(m*128+k)*128 + n]  (m=0:W1a, 1:W1b, 2:W1c; transposed)
__global__ void prep_w1t(const float* __restrict__ W1, ushort_t* wh, ushort_t* wl) {
    int idx = blockIdx.x * 256 + threadIdx.x;
    if (idx >= 3 * 128 * 128) return;
    int m = idx >> 14, n = (idx >> 7) & 127, k = idx & 127;
    float v = W1[(m * 128 + k) * 128 + n];
    ushort_t h = f2bf(v);
    wh[idx] = h;
    wl[idx] = f2bf(v - bf2f(h));
}

// ---------------- CSR build ----------------
__global__ void zero_ints(int* p, int n) {
    int i = blockIdx.x * 256 + threadIdx.x;
    if (i < n) p[i] = 0;
}

__global__ void count_deg(const int* __restrict__ dstI, const int* __restrict__ dstD,
                          int* cnt, int N, int E) {
    int e = blockIdx.x * 256 + threadIdx.x;
    if (e < E) {
        atomicAdd(&cnt[dstI[e]], 1);
        atomicAdd(&cnt[N + dstD[e]], 1);
    }
}

__global__ void make_dinv(const int* __restrict__ cnt, float* dI, float* dD, int N) {
    int i = blockIdx.x * 256 + threadIdx.x;
    if (i < N) {
        dI[i] = rsqrtf((float)(cnt[i] + 1));
        dD[i] = rsqrtf((float)(cnt[N + i] + 1));
    }
}

__global__ void scan_partial(const int* __restrict__ cnt, int* partials, int n2) {
    __shared__ int sdata[256];
    int i = blockIdx.x * 256 + threadIdx.x;
    sdata[threadIdx.x] = (i < n2) ? cnt[i] : 0;
    __syncthreads();
    for (int s = 128; s > 0; s >>= 1) {
        if (threadIdx.x < s) sdata[threadIdx.x] += sdata[threadIdx.x + s];
        __syncthreads();
    }
    if (threadIdx.x == 0) partials[blockIdx.x] = sdata[0];
}

__global__ void scan_partials_excl(int* partials, int nb) {
    if (blockIdx.x == 0 && threadIdx.x == 0) {
        int acc = 0;
        for (int i = 0; i < nb; ++i) { int t = partials[i]; partials[i] = acc; acc += t; }
    }
}

__global__ void scan_final(const int* __restrict__ cnt, const int* __restrict__ partials,
                           int* off, int* cur, int n2) {
    __shared__ int sdata[256];
    int i = blockIdx.x * 256 + threadIdx.x;
    int v = (i < n2) ? cnt[i] : 0;
    sdata[threadIdx.x] = v;
    __syncthreads();
    for (int s = 1; s < 256; s <<= 1) {
        int t = (threadIdx.x >= s) ? sdata[threadIdx.x - s] : 0;
        __syncthreads();
        sdata[threadIdx.x] += t;
        __syncthreads();
    }
    int excl = sdata[threadIdx.x] - v + partials[blockIdx.x];
    if (i < n2) { off[i] = excl; cur[i] = excl; }
}

__global__ void fill_csr(const int* __restrict__ srcI, const int* __restrict__ dstI,
                         const int* __restrict__ srcD, const int* __restrict__ dstD,
                         const float* __restrict__ dI, const float* __restrict__ dD,
                         int* cur, int* srcs, float* coefs, int N, int E) {
    int e = blockIdx.x * 256 + threadIdx.x;
    if (e < E) {
        int s = srcI[e], d = dstI[e];
        int pos = atomicAdd(&cur[d], 1);
        srcs[pos] = s;
        coefs[pos] = dI[s] * dI[d];
        s = srcD[e]; d = dstD[e];
        pos = atomicAdd(&cur[N + d], 1);
        srcs[pos] = s;
        coefs[pos] = dD[s] * dD[d];
    }
}

// ---------------- gather: one wave per node, both graphs, 4-deep ILP ----------------
__global__ __launch_bounds__(256) void gather_combine2(
    const float* __restrict__ xl,
    const int* __restrict__ off, const int* __restrict__ srcs,
    const float* __restrict__ coefs,
    const float* __restrict__ dI, const float* __restrict__ dD,
    const float* __restrict__ bconv, float* __restrict__ z, int N, int E2) {
    int d = blockIdx.x * 4 + (threadIdx.x >> 6);
    int lane = threadIdx.x & 63;
    if (d >= N) return;
    const float2* x2 = (const float2*)xl;
    float2 xd = x2[(long)d * 64 + lane];
    float aI = dI[d], aD = dD[d];
    float2 accI, accD;
    {
        float c = aI * aI;
        accI.x = c * xd.x; accI.y = c * xd.y;
        c = aD * aD;
        accD.x = c * xd.x; accD.y = c * xd.y;
    }
#pragma unroll
    for (int g = 0; g < 2; ++g) {
        int s0 = (g == 0) ? off[d] : off[N + d];
        int e0 = (g == 0) ? off[d + 1] : ((d == N - 1) ? E2 : off[N + d + 1]);
        float2 a0 = {0.f, 0.f}, a1 = {0.f, 0.f}, a2 = {0.f, 0.f}, a3 = {0.f, 0.f};
        for (int k0 = s0; k0 < e0; k0 += 64) {
            int nk = min(64, e0 - k0);
            int sv = (lane < nk) ? srcs[k0 + lane] : 0;
            float cv = (lane < nk) ? coefs[k0 + lane] : 0.f;
            for (int k = 0; k < nk; k += 4) {
                int i0 = __builtin_amdgcn_readlane(sv, k);
                int i1 = __builtin_amdgcn_readlane(sv, k + 1);
                int i2 = __builtin_amdgcn_readlane(sv, k + 2);
                int i3 = __builtin_amdgcn_readlane(sv, k + 3);
                float c0 = readlane_f(cv, k);
                float c1 = readlane_f(cv, k + 1);
                float c2 = readlane_f(cv, k + 2);
                float c3 = readlane_f(cv, k + 3);
                float2 r0 = x2[(long)i0 * 64 + lane];
                float2 r1 = x2[(long)i1 * 64 + lane];
                float2 r2 = x2[(long)i2 * 64 + lane];
                float2 r3 = x2[(long)i3 * 64 + lane];
                a0.x = fmaf(c0, r0.x, a0.x); a0.y = fmaf(c0, r0.y, a0.y);
                a1.x = fmaf(c1, r1.x, a1.x); a1.y = fmaf(c1, r1.y, a1.y);
                a2.x = fmaf(c2, r2.x, a2.x); a2.y = fmaf(c2, r2.y, a2.y);
                a3.x = fmaf(c3, r3.x, a3.x); a3.y = fmaf(c3, r3.y, a3.y);
            }
        }
        float sx = (a0.x + a1.x) + (a2.x + a3.x);
        float sy = (a0.y + a1.y) + (a2.y + a3.y);
        if (g == 0) { accI.x += sx; accI.y += sy; }
        else        { accD.x += sx; accD.y += sy; }
    }
    float2 b = ((const float2*)bconv)[lane];
    float2 r;
    r.x = fmaxf(accI.x + b.x, 0.f) + fmaxf(accD.x + b.x, 0.f);
    r.y = fmaxf(accI.y + b.y, 0.f) + fmaxf(accD.y + b.y, 0.f);
    ((float2*)z)[(long)d * 64 + lane] = r;
}

// ---------------- decode: fused 3-matvec MFMA, no UV gathers ----------------
// out[p] = relu( zi@W1a + zj@W1b + |zi-zj|@W1c + b1 ) @ W2 + b2
#define RUN_PHASE(mph, AH, AL)                                                          \
    {                                                                                   \
        __syncthreads();                                                                \
        const float4* ph4 = (const float4*)(w1th + (mph) * 16384);                      \
        const float4* pl4 = (const float4*)(w1tl + (mph) * 16384);                      \
        for (int t2 = tid; t2 < 2048; t2 += 256) {                                      \
            int n = t2 >> 4, c8 = t2 & 15;                                              \
            *(float4*)&Wh[n][c8 * 8] = ph4[t2];                                         \
            *(float4*)&Wl[n][c8 * 8] = pl4[t2];                                         \
        }                                                                               \
        __syncthreads();                                                                \
        if (active) {                                                                   \
            _Pragma("unroll")                                                           \
            for (int t = 0; t < 8; ++t) {                                               \
                _Pragma("unroll")                                                       \
                for (int kk = 0; kk < 4; ++kk) {                                        \
                    short8 bh = *(const short8*)&Wh[16 * t + r][kk * 32 + q * 8];       \
                    short8 bl = *(const short8*)&Wl[16 * t + r][kk * 32 + q * 8];       \
                    acc[t] = __builtin_amdgcn_mfma_f32_16x16x32_bf16(AH[kk], bh, acc[t], 0, 0, 0); \
                    acc[t] = __builtin_amdgcn_mfma_f32_16x16x32_bf16(AL[kk], bh, acc[t], 0, 0, 0); \
                    acc[t] = __builtin_amdgcn_mfma_f32_16x16x32_bf16(AH[kk], bl, acc[t], 0, 0, 0); \
                }                                                                       \
            }                                                                           \
        }                                                                               \
    }

__global__ __launch_bounds__(256) void decode_mfma2(
    const float* __restrict__ z,
    const int* __restrict__ ei, const int* __restrict__ ej,
    const ushort_t* __restrict__ w1th, const ushort_t* __restrict__ w1tl,
    const float* __restrict__ b1, const float* __restrict__ W2, const float* __restrict__ b2,
    float* __restrict__ out, int P) {
    __shared__ ushort_t Wh[128][136];
    __shared__ ushort_t Wl[128][136];
    int tid = threadIdx.x;
    int lane = tid & 63, w = tid >> 6;
    int r = lane & 15, q = lane >> 4;
    int base = blockIdx.x * 64 + w * 16;
    bool active = base < P;
    int iv = 0, jv = 0;
    if (active && lane < 16) {
        int p = min(base + lane, P - 1);
        iv = ei[p]; jv = ej[p];
    }
    // NOTE: divergent lane index -> must use __shfl (ds_bpermute), NOT readlane
    int myi = __shfl(iv, r, 64);
    int myj = __shfl(jv, r, 64);

    // load zi/zj fragments directly from global (row = pair r, features q*8 + kk*32 + e)
    short8 zih[4], zil[4], zjh[4], zjl[4];
    if (active) {
        const float* zi = z + (long)myi * 128 + q * 8;
        const float* zj = z + (long)myj * 128 + q * 8;
#pragma unroll
        for (int kk = 0; kk < 4; ++kk) {
            float v8[8];
            *(float4*)&v8[0] = *(const float4*)(zi + kk * 32);
            *(float4*)&v8[4] = *(const float4*)(zi + kk * 32 + 4);
            pack_hilo(v8, zih[kk], zil[kk]);
            *(float4*)&v8[0] = *(const float4*)(zj + kk * 32);
            *(float4*)&v8[4] = *(const float4*)(zj + kk * 32 + 4);
            pack_hilo(v8, zjh[kk], zjl[kk]);
        }
    }

    f32x4 acc[8] = {};
    RUN_PHASE(0, zih, zil);   // zi @ W1a
    RUN_PHASE(1, zjh, zjl);   // zj @ W1b

    // d = |zi - zj| fragments (reconstructed from hi/lo, exact to ~2^-17)
    short8 dh[4], dl[4];
    if (active) {
#pragma unroll
        for (int kk = 0; kk < 4; ++kk) {
            float v8[8];
#pragma unroll
            for (int e = 0; e < 8; ++e) {
                float a = bf2f((ushort_t)zih[kk][e]) + bf2f((ushort_t)zil[kk][e]);
                float b = bf2f((ushort_t)zjh[kk][e]) + bf2f((ushort_t)zjl[kk][e]);
                v8[e] = fabsf(a - b);
            }
            pack_hilo(v8, dh[kk], dl[kk]);
        }
    }
    RUN_PHASE(2, dh, dl);     // |zi-zj| @ W1c

    if (!active) return;
    float b2v = b2[0];
    float b1c[8], w2c[8];
#pragma unroll
    for (int t = 0; t < 8; ++t) {
        int col = 16 * t + r;
        b1c[t] = b1[col];
        w2c[t] = W2[col];
    }
#pragma unroll
    for (int r2 = 0; r2 < 4; ++r2) {
        int row = q * 4 + r2;                 // C layout: row = (lane>>4)*4 + reg
        float s = 0.f;
#pragma unroll
        for (int t = 0; t < 8; ++t) {
            float h = acc[t][r2] + b1c[t];    // col = 16t + (lane&15)
            s += fmaxf(h, 0.f) * w2c[t];
        }
        s += __shfl_xor(s, 1, 64);
        s += __shfl_xor(s, 2, 64);
        s += __shfl_xor(s, 4, 64);
        s += __shfl_xor(s, 8, 64);
        int gp = base + row;
        if (r == 0 && gp < P) out[gp] = s + b2v;
    }
}

extern "C" void kernel_launch(void* const* d_in, const int* in_sizes, int n_in,
                              void* d_out, int out_size, void* d_ws, size_t ws_size,
                              hipStream_t stream) {
    const float* x  = (const float*)d_in[0];
    const int*   eI = (const int*)d_in[1];
    const int*   eD = (const int*)d_in[2];
    const int*   eL = (const int*)d_in[3];
    const float* Wconv = (const float*)d_in[4];
    const float* bconv = (const float*)d_in[5];
    const float* W1 = (const float*)d_in[6];
    const float* b1 = (const float*)d_in[7];
    const float* W2 = (const float*)d_in[8];
    const float* b2 = (const float*)d_in[9];

    int N = in_sizes[0] / 256;
    int E = in_sizes[1] / 2;
    int P = in_sizes[3] / 2;
    long NH = (long)N * 128;

    // ---- workspace layout ----
    float* ws = (float*)d_ws;
    float* xl = ws;                 // NH
    float* z  = xl + NH;            // NH
    float* dI = z + NH;             // N
    float* dD = dI + N;             // N
    int* iws = (int*)(dD + N);
    int n2 = 2 * N;
    int* cnt = iws;                 // 2N
    int* off = cnt + n2;            // 2N
    int* cur = off + n2;            // 2N
    int nb = (n2 + 255) / 256;
    int* partials = cur + n2;       // padded to 64
    int* srcs = partials + ((nb + 63) & ~63);       // 2E ints
    float* coefs = (float*)(srcs + 2 * (long)E);    // 2E floats
    ushort_t* w1th = (ushort_t*)(coefs + 2 * (long)E);  // 3*16384
    ushort_t* w1tl = w1th + 3 * 16384;                  // 3*16384
    ushort_t* btch = w1tl + 3 * 16384;                  // 32768
    ushort_t* btcl = btch + 32768;                      // 32768
    float* out = (float*)d_out;

    // weight preps
    prep_bt_conv<<<128, 256, 0, stream>>>(Wconv, btch, btcl);
    prep_w1t<<<192, 256, 0, stream>>>(W1, w1th, w1tl);

    // xl = x @ W_conv   (MFMA hi/lo split)
    dim3 gx((N + 127) / 128, 1);
    gemm_mfma_hilo<<<gx, 256, 0, stream>>>(x, btch, btcl, xl, N, 256, 128);

    // CSR build
    zero_ints<<<(n2 + 255) / 256, 256, 0, stream>>>(cnt, n2);
    count_deg<<<(E + 255) / 256, 256, 0, stream>>>(eI + E, eD + E, cnt, N, E);
    make_dinv<<<(N + 255) / 256, 256, 0, stream>>>(cnt, dI, dD, N);
    scan_partial<<<nb, 256, 0, stream>>>(cnt, partials, n2);
    scan_partials_excl<<<1, 64, 0, stream>>>(partials, nb);
    scan_final<<<nb, 256, 0, stream>>>(cnt, partials, off, cur, n2);
    fill_csr<<<(E + 255) / 256, 256, 0, stream>>>(eI, eI + E, eD, eD + E, dI, dD,
                                                  cur, srcs, coefs, N, E);

    // gather + combine -> z
    gather_combine2<<<(N + 3) / 4, 256, 0, stream>>>(xl, off, srcs, coefs, dI, dD,
                                                     bconv, z, N, 2 * E);

    // decode (fused 3-matvec)
    decode_mfma2<<<(P + 63) / 64, 256, 0, stream>>>(z, eL, eL + P, w1th, w1tl,
                                                    b1, W2, b2, out, P);
}

// Round 8
// 544.904 us; speedup vs baseline: 1.1505x; 1.1505x over previous
//
#include <hip/hip_runtime.h>

typedef short short8 __attribute__((ext_vector_type(8)));
typedef float f32x4 __attribute__((ext_vector_type(4)));
typedef float f32x16 __attribute__((ext_vector_type(16)));
typedef unsigned short ushort_t;
typedef unsigned int uint_t;

#define HD __device__ __forceinline__

HD ushort_t f2bf(float f) {  // round-to-nearest-even f32 -> bf16 bits
    uint_t u = __float_as_uint(f);
    uint_t r = (u + 0x7fffu + ((u >> 16) & 1u)) >> 16;
    return (ushort_t)r;
}
HD float bf2f(ushort_t h) { return __uint_as_float(((uint_t)h) << 16); }
HD float readlane_f(float v, int l) {
    return __int_as_float(__builtin_amdgcn_readlane(__float_as_int(v), l));
}

HD void pack_hilo(const float* v8, short8& h, short8& l) {
#pragma unroll
    for (int e = 0; e < 8; ++e) {
        ushort_t hh = f2bf(v8[e]);
        h[e] = (short)hh;
        l[e] = (short)f2bf(v8[e] - bf2f(hh));
    }
}

// ---------------- MFMA hi/lo split GEMM: C[M,Ntot] = A[M,K] @ B ----------------
__global__ __launch_bounds__(256) void gemm_mfma_hilo(
    const float* __restrict__ A, const ushort_t* __restrict__ Bth,
    const ushort_t* __restrict__ Btl, float* __restrict__ C,
    int M, int K, int Ntot) {
    __shared__ ushort_t Ah[128][72], Al[128][72], Bh[128][72], Bl[128][72];
    int tid = threadIdx.x;
    int lane = tid & 63, w = tid >> 6;
    int row0 = blockIdx.x * 128;
    int col0 = blockIdx.y * 128;
    int cl = lane & 31, hi = lane >> 5;
    f32x16 acc[4] = {};
    for (int k0 = 0; k0 < K; k0 += 64) {
        for (int e = tid; e < 4096; e += 256) {
            int r = e >> 5, k2 = e & 31;
            int gr = row0 + r;
            float2 v = {0.f, 0.f};
            if (gr < M) v = *(const float2*)&A[(long)gr * K + k0 + k2 * 2];
            ushort_t h0 = f2bf(v.x); ushort_t l0 = f2bf(v.x - bf2f(h0));
            ushort_t h1 = f2bf(v.y); ushort_t l1 = f2bf(v.y - bf2f(h1));
            *(uint_t*)&Ah[r][k2 * 2] = (uint_t)h0 | ((uint_t)h1 << 16);
            *(uint_t*)&Al[r][k2 * 2] = (uint_t)l0 | ((uint_t)l1 << 16);
        }
        for (int e = tid; e < 4096; e += 256) {
            int n = e >> 5, k2 = e & 31;
            const uint_t* ph = (const uint_t*)&Bth[(long)(col0 + n) * K + k0];
            const uint_t* pl = (const uint_t*)&Btl[(long)(col0 + n) * K + k0];
            *(uint_t*)&Bh[n][k2 * 2] = ph[k2];
            *(uint_t*)&Bl[n][k2 * 2] = pl[k2];
        }
        __syncthreads();
        int arow = w * 32 + cl;
#pragma unroll
        for (int kk = 0; kk < 4; ++kk) {
            int koff = kk * 16 + hi * 8;
            short8 a_h = *(const short8*)&Ah[arow][koff];
            short8 a_l = *(const short8*)&Al[arow][koff];
#pragma unroll
            for (int nf = 0; nf < 4; ++nf) {
                int bcol = nf * 32 + cl;
                short8 b_h = *(const short8*)&Bh[bcol][koff];
                short8 b_l = *(const short8*)&Bl[bcol][koff];
                acc[nf] = __builtin_amdgcn_mfma_f32_32x32x16_bf16(a_h, b_h, acc[nf], 0, 0, 0);
                acc[nf] = __builtin_amdgcn_mfma_f32_32x32x16_bf16(a_l, b_h, acc[nf], 0, 0, 0);
                acc[nf] = __builtin_amdgcn_mfma_f32_32x32x16_bf16(a_h, b_l, acc[nf], 0, 0, 0);
            }
        }
        __syncthreads();
    }
#pragma unroll
    for (int nf = 0; nf < 4; ++nf) {
#pragma unroll
        for (int reg = 0; reg < 16; ++reg) {
            int crow = (reg & 3) + 8 * (reg >> 2) + 4 * hi + w * 32;
            int gr = row0 + crow;
            if (gr < M) C[(long)gr * Ntot + col0 + nf * 32 + cl] = acc[nf][reg];
        }
    }
}

// ---------------- weight prep ----------------
__global__ void prep_bt_conv(const float* __restrict__ Wc, ushort_t* bh, ushort_t* bl) {
    int idx = blockIdx.x * 256 + threadIdx.x;
    if (idx >= 128 * 256) return;
    int n = idx >> 8, k = idx & 255;
    float v = Wc[k * 128 + n];
    ushort_t h = f2bf(v);
    bh[idx] = h;
    bl[idx] = f2bf(v - bf2f(h));
}

// W1 (a,b,c blocks) in MFMA B-fragment order, bf16-hi only:
// w1f[m*16384 + f*512 + l*8 + e] = bf16(W1[(m*128 + k)*128 + col])
//   f = t*4+kk (t=0..7 col-tile, kk=0..3 k-tile), l = lane, e = elem
//   col = 16t + (l&15), k = kk*32 + (l>>4)*8 + e
// -> every decode ds_read_b128 is wave-contiguous (conflict-free).
__global__ void prep_w1frag(const float* __restrict__ W1, ushort_t* __restrict__ w1f) {
    int idx = blockIdx.x * 256 + threadIdx.x;
    if (idx >= 3 * 16384) return;
    int m = idx >> 14;
    int rem = idx & 16383;
    int f = rem >> 9, l = (rem >> 3) & 63, e = rem & 7;
    int t = f >> 2, kk = f & 3;
    int col = 16 * t + (l & 15);
    int k = kk * 32 + (l >> 4) * 8 + e;
    w1f[idx] = f2bf(W1[(m * 128 + k) * 128 + col]);
}

// ---------------- CSR build ----------------
__global__ void zero_ints(int* p, int n) {
    int i = blockIdx.x * 256 + threadIdx.x;
    if (i < n) p[i] = 0;
}

__global__ void count_deg(const int* __restrict__ dstI, const int* __restrict__ dstD,
                          int* cnt, int N, int E) {
    int e = blockIdx.x * 256 + threadIdx.x;
    if (e < E) {
        atomicAdd(&cnt[dstI[e]], 1);
        atomicAdd(&cnt[N + dstD[e]], 1);
    }
}

__global__ void make_dinv(const int* __restrict__ cnt, float* dI, float* dD, int N) {
    int i = blockIdx.x * 256 + threadIdx.x;
    if (i < N) {
        dI[i] = rsqrtf((float)(cnt[i] + 1));
        dD[i] = rsqrtf((float)(cnt[N + i] + 1));
    }
}

__global__ void scan_partial(const int* __restrict__ cnt, int* partials, int n2) {
    __shared__ int sdata[256];
    int i = blockIdx.x * 256 + threadIdx.x;
    sdata[threadIdx.x] = (i < n2) ? cnt[i] : 0;
    __syncthreads();
    for (int s = 128; s > 0; s >>= 1) {
        if (threadIdx.x < s) sdata[threadIdx.x] += sdata[threadIdx.x + s];
        __syncthreads();
    }
    if (threadIdx.x == 0) partials[blockIdx.x] = sdata[0];
}

__global__ void scan_partials_excl(int* partials, int nb) {
    if (blockIdx.x == 0 && threadIdx.x == 0) {
        int acc = 0;
        for (int i = 0; i < nb; ++i) { int t = partials[i]; partials[i] = acc; acc += t; }
    }
}

__global__ void scan_final(const int* __restrict__ cnt, const int* __restrict__ partials,
                           int* off, int* cur, int n2) {
    __shared__ int sdata[256];
    int i = blockIdx.x * 256 + threadIdx.x;
    int v = (i < n2) ? cnt[i] : 0;
    sdata[threadIdx.x] = v;
    __syncthreads();
    for (int s = 1; s < 256; s <<= 1) {
        int t = (threadIdx.x >= s) ? sdata[threadIdx.x - s] : 0;
        __syncthreads();
        sdata[threadIdx.x] += t;
        __syncthreads();
    }
    int excl = sdata[threadIdx.x] - v + partials[blockIdx.x];
    if (i < n2) { off[i] = excl; cur[i] = excl; }
}

__global__ void fill_csr(const int* __restrict__ srcI, const int* __restrict__ dstI,
                         const int* __restrict__ srcD, const int* __restrict__ dstD,
                         const float* __restrict__ dI, const float* __restrict__ dD,
                         int* cur, int* srcs, float* coefs, int N, int E) {
    int e = blockIdx.x * 256 + threadIdx.x;
    if (e < E) {
        int s = srcI[e], d = dstI[e];
        int pos = atomicAdd(&cur[d], 1);
        srcs[pos] = s;
        coefs[pos] = dI[s] * dI[d];
        s = srcD[e]; d = dstD[e];
        pos = atomicAdd(&cur[N + d], 1);
        srcs[pos] = s;
        coefs[pos] = dD[s] * dD[d];
    }
}

// ---------------- gather: one wave per node, both graphs, 4-deep ILP ----------------
__global__ __launch_bounds__(256) void gather_combine2(
    const float* __restrict__ xl,
    const int* __restrict__ off, const int* __restrict__ srcs,
    const float* __restrict__ coefs,
    const float* __restrict__ dI, const float* __restrict__ dD,
    const float* __restrict__ bconv, float* __restrict__ z, int N, int E2) {
    int d = blockIdx.x * 4 + (threadIdx.x >> 6);
    int lane = threadIdx.x & 63;
    if (d >= N) return;
    const float2* x2 = (const float2*)xl;
    float2 xd = x2[(long)d * 64 + lane];
    float aI = dI[d], aD = dD[d];
    float2 accI, accD;
    {
        float c = aI * aI;
        accI.x = c * xd.x; accI.y = c * xd.y;
        c = aD * aD;
        accD.x = c * xd.x; accD.y = c * xd.y;
    }
#pragma unroll
    for (int g = 0; g < 2; ++g) {
        int s0 = (g == 0) ? off[d] : off[N + d];
        int e0 = (g == 0) ? off[d + 1] : ((d == N - 1) ? E2 : off[N + d + 1]);
        float2 a0 = {0.f, 0.f}, a1 = {0.f, 0.f}, a2 = {0.f, 0.f}, a3 = {0.f, 0.f};
        for (int k0 = s0; k0 < e0; k0 += 64) {
            int nk = min(64, e0 - k0);
            int sv = (lane < nk) ? srcs[k0 + lane] : 0;
            float cv = (lane < nk) ? coefs[k0 + lane] : 0.f;
            for (int k = 0; k < nk; k += 4) {
                int i0 = __builtin_amdgcn_readlane(sv, k);
                int i1 = __builtin_amdgcn_readlane(sv, k + 1);
                int i2 = __builtin_amdgcn_readlane(sv, k + 2);
                int i3 = __builtin_amdgcn_readlane(sv, k + 3);
                float c0 = readlane_f(cv, k);
                float c1 = readlane_f(cv, k + 1);
                float c2 = readlane_f(cv, k + 2);
                float c3 = readlane_f(cv, k + 3);
                float2 r0 = x2[(long)i0 * 64 + lane];
                float2 r1 = x2[(long)i1 * 64 + lane];
                float2 r2 = x2[(long)i2 * 64 + lane];
                float2 r3 = x2[(long)i3 * 64 + lane];
                a0.x = fmaf(c0, r0.x, a0.x); a0.y = fmaf(c0, r0.y, a0.y);
                a1.x = fmaf(c1, r1.x, a1.x); a1.y = fmaf(c1, r1.y, a1.y);
                a2.x = fmaf(c2, r2.x, a2.x); a2.y = fmaf(c2, r2.y, a2.y);
                a3.x = fmaf(c3, r3.x, a3.x); a3.y = fmaf(c3, r3.y, a3.y);
            }
        }
        float sx = (a0.x + a1.x) + (a2.x + a3.x);
        float sy = (a0.y + a1.y) + (a2.y + a3.y);
        if (g == 0) { accI.x += sx; accI.y += sy; }
        else        { accD.x += sx; accD.y += sy; }
    }
    float2 b = ((const float2*)bconv)[lane];
    float2 r;
    r.x = fmaxf(accI.x + b.x, 0.f) + fmaxf(accD.x + b.x, 0.f);
    r.y = fmaxf(accI.y + b.y, 0.f) + fmaxf(accD.y + b.y, 0.f);
    ((float2*)z)[(long)d * 64 + lane] = r;
}

// ---------------- decode: fused 3-matvec MFMA, fragment-order W ----------------
// out[p] = relu( zi@W1a + zj@W1b + |zi-zj|@W1c + b1 ) @ W2 + b2
// A hi/lo split (2 products, near-fp32); B = bf16 W1 fragments, conflict-free LDS.
__global__ __launch_bounds__(256) void decode_mfma3(
    const float* __restrict__ z,
    const int* __restrict__ ei, const int* __restrict__ ej,
    const ushort_t* __restrict__ w1f,
    const float* __restrict__ b1, const float* __restrict__ W2, const float* __restrict__ b2,
    float* __restrict__ out, int P) {
    __shared__ ushort_t Wlds[16384];  // 32 KB, restaged per phase
    int tid = threadIdx.x;
    int lane = tid & 63, w = tid >> 6;
    int r = lane & 15, q = lane >> 4;
    int base = blockIdx.x * 64 + w * 16;
    bool active = base < P;
    int iv = 0, jv = 0;
    if (active && lane < 16) {
        int p = min(base + lane, P - 1);
        iv = ei[p]; jv = ej[p];
    }
    // divergent lane index -> __shfl (ds_bpermute), NOT readlane
    int myi = __shfl(iv, r, 64);
    int myj = __shfl(jv, r, 64);

    // A-fragments straight from global: pair row r, features kk*32 + q*8 + e
    short8 zih[4], zil[4], zjh[4], zjl[4];
    if (active) {
        const float* zi = z + (long)myi * 128 + q * 8;
        const float* zj = z + (long)myj * 128 + q * 8;
#pragma unroll
        for (int kk = 0; kk < 4; ++kk) {
            float v8[8];
            *(float4*)&v8[0] = *(const float4*)(zi + kk * 32);
            *(float4*)&v8[4] = *(const float4*)(zi + kk * 32 + 4);
            pack_hilo(v8, zih[kk], zil[kk]);
            *(float4*)&v8[0] = *(const float4*)(zj + kk * 32);
            *(float4*)&v8[4] = *(const float4*)(zj + kk * 32 + 4);
            pack_hilo(v8, zjh[kk], zjl[kk]);
        }
    }

    f32x4 acc[8] = {};

#define STAGE_W(mph)                                                            \
    {                                                                           \
        __syncthreads();                                                        \
        const float4* src4 = (const float4*)(w1f + (mph) * 16384);              \
        _Pragma("unroll")                                                       \
        for (int t2 = 0; t2 < 8; ++t2)                                          \
            ((float4*)Wlds)[t2 * 256 + tid] = src4[t2 * 256 + tid];             \
        __syncthreads();                                                        \
    }

#define COMPUTE(AH, AL)                                                         \
    if (active) {                                                               \
        _Pragma("unroll")                                                       \
        for (int t = 0; t < 8; ++t) {                                           \
            _Pragma("unroll")                                                   \
            for (int kk = 0; kk < 4; ++kk) {                                    \
                short8 bh = *(const short8*)&Wlds[(t * 4 + kk) * 512 + lane * 8]; \
                acc[t] = __builtin_amdgcn_mfma_f32_16x16x32_bf16(AH[kk], bh, acc[t], 0, 0, 0); \
                acc[t] = __builtin_amdgcn_mfma_f32_16x16x32_bf16(AL[kk], bh, acc[t], 0, 0, 0); \
            }                                                                   \
        }                                                                       \
    }

    STAGE_W(0);
    COMPUTE(zih, zil);      // zi @ W1a
    STAGE_W(1);
    COMPUTE(zjh, zjl);      // zj @ W1b

    // d = |zi - zj| (hi/lo reconstruction is exact to ~2^-17)
    short8 dh[4], dl[4];
    if (active) {
#pragma unroll
        for (int kk = 0; kk < 4; ++kk) {
            float v8[8];
#pragma unroll
            for (int e = 0; e < 8; ++e) {
                float a = bf2f((ushort_t)zih[kk][e]) + bf2f((ushort_t)zil[kk][e]);
                float b = bf2f((ushort_t)zjh[kk][e]) + bf2f((ushort_t)zjl[kk][e]);
                v8[e] = fabsf(a - b);
            }
            pack_hilo(v8, dh[kk], dl[kk]);
        }
    }
    STAGE_W(2);
    COMPUTE(dh, dl);        // |zi-zj| @ W1c

#undef STAGE_W
#undef COMPUTE

    if (!active) return;
    float b2v = b2[0];
    float b1c[8], w2c[8];
#pragma unroll
    for (int t = 0; t < 8; ++t) {
        int col = 16 * t + r;
        b1c[t] = b1[col];
        w2c[t] = W2[col];
    }
#pragma unroll
    for (int r2 = 0; r2 < 4; ++r2) {
        int row = q * 4 + r2;                 // C layout: row = (lane>>4)*4 + reg
        float s = 0.f;
#pragma unroll
        for (int t = 0; t < 8; ++t) {
            float h = acc[t][r2] + b1c[t];    // col = 16t + (lane&15)
            s += fmaxf(h, 0.f) * w2c[t];
        }
        s += __shfl_xor(s, 1, 64);
        s += __shfl_xor(s, 2, 64);
        s += __shfl_xor(s, 4, 64);
        s += __shfl_xor(s, 8, 64);
        int gp = base + row;
        if (r == 0 && gp < P) out[gp] = s + b2v;
    }
}

extern "C" void kernel_launch(void* const* d_in, const int* in_sizes, int n_in,
                              void* d_out, int out_size, void* d_ws, size_t ws_size,
                              hipStream_t stream) {
    const float* x  = (const float*)d_in[0];
    const int*   eI = (const int*)d_in[1];
    const int*   eD = (const int*)d_in[2];
    const int*   eL = (const int*)d_in[3];
    const float* Wconv = (const float*)d_in[4];
    const float* bconv = (const float*)d_in[5];
    const float* W1 = (const float*)d_in[6];
    const float* b1 = (const float*)d_in[7];
    const float* W2 = (const float*)d_in[8];
    const float* b2 = (const float*)d_in[9];

    int N = in_sizes[0] / 256;
    int E = in_sizes[1] / 2;
    int P = in_sizes[3] / 2;
    long NH = (long)N * 128;

    // ---- workspace layout ----
    float* ws = (float*)d_ws;
    float* xl = ws;                 // NH
    float* z  = xl + NH;            // NH
    float* dI = z + NH;             // N
    float* dD = dI + N;             // N
    int* iws = (int*)(dD + N);
    int n2 = 2 * N;
    int* cnt = iws;                 // 2N
    int* off = cnt + n2;            // 2N
    int* cur = off + n2;            // 2N
    int nb = (n2 + 255) / 256;
    int* partials = cur + n2;       // padded to 64
    int* srcs = partials + ((nb + 63) & ~63);       // 2E ints
    float* coefs = (float*)(srcs + 2 * (long)E);    // 2E floats
    ushort_t* w1f = (ushort_t*)(coefs + 2 * (long)E);   // 3*16384 (fragment order)
    ushort_t* btch = w1f + 3 * 16384;                   // 32768
    ushort_t* btcl = btch + 32768;                      // 32768
    float* out = (float*)d_out;

    // weight preps
    prep_bt_conv<<<128, 256, 0, stream>>>(Wconv, btch, btcl);
    prep_w1frag<<<192, 256, 0, stream>>>(W1, w1f);

    // xl = x @ W_conv   (MFMA hi/lo split)
    dim3 gx((N + 127) / 128, 1);
    gemm_mfma_hilo<<<gx, 256, 0, stream>>>(x, btch, btcl, xl, N, 256, 128);

    // CSR build
    zero_ints<<<(n2 + 255) / 256, 256, 0, stream>>>(cnt, n2);
    count_deg<<<(E + 255) / 256, 256, 0, stream>>>(eI + E, eD + E, cnt, N, E);
    make_dinv<<<(N + 255) / 256, 256, 0, stream>>>(cnt, dI, dD, N);
    scan_partial<<<nb, 256, 0, stream>>>(cnt, partials, n2);
    scan_partials_excl<<<1, 64, 0, stream>>>(partials, nb);
    scan_final<<<nb, 256, 0, stream>>>(cnt, partials, off, cur, n2);
    fill_csr<<<(E + 255) / 256, 256, 0, stream>>>(eI, eI + E, eD, eD + E, dI, dD,
                                                  cur, srcs, coefs, N, E);

    // gather + combine -> z
    gather_combine2<<<(N + 3) / 4, 256, 0, stream>>>(xl, off, srcs, coefs, dI, dD,
                                                     bconv, z, N, 2 * E);

    // decode (fused 3-matvec, fragment-order W)
    decode_mfma3<<<(P + 63) / 64, 256, 0, stream>>>(z, eL, eL + P, w1f,
                                                    b1, W2, b2, out, P);
}